// Round 9
// baseline (147.934 us; speedup 1.0000x reference)
//
#include <hip/hip_runtime.h>

// STGraphConstructor: adj[b] = tanh(relu(A_b A_b^T) + I), A_b = [5096 x 64] fp32.
// R9: persistent band-sweep blocks + double-buffered col panel.
//  - R8 (109 us) validated: LDS-staged inputs + swapped-operand MFMA + float4
//    bursts. Remaining: redundant row-panel staging (40x), 6400 cold starts,
//    no page continuation between a row's fragments.
//  - 512 blocks (exactly 2/CU, even 12/13-tile split). Block owns contiguous
//    (bi,bj) range, bj-fastest: A-frags in REGISTERS once per band; col panel
//    double-buffered 2x32KB LDS (still 64KB, 2 blk/CU). Async staging split:
//    global loads early (hide under MFMA), ds_write late, 1 barrier/tile.
//  - Stores: block sweeps its 128-row band left->right => per-row sequential
//    512B fragments (DRAM page continuation), 512 steady streams.
//  - prep kernel + hi/lo x3 MFMA + XOR swizzle + exp2-tanh unchanged (proven).

#define NSP 5000
#define NTM 96
#define MM  5096
#define DD  64
#define BT  128
#define NTILE 40   // col tiles per band

typedef __attribute__((ext_vector_type(8))) short short8;
typedef __attribute__((ext_vector_type(8))) unsigned short ushort8;
typedef __attribute__((ext_vector_type(4))) float f32x4;

__device__ __forceinline__ unsigned short bf16_rn(float x) {
  unsigned u = __float_as_uint(x);
  u += 0x7FFFu + ((u >> 16) & 1u);
  return (unsigned short)(u >> 16);
}
__device__ __forceinline__ float bf16_f32(unsigned short s) {
  return __uint_as_float(((unsigned)s) << 16);
}

// ---- prep: convert concat(sp,tm) [B][MM][DD] fp32 -> hi/lo bf16 panels ----
__global__ __launch_bounds__(256) void stg_prep_kernel(
    const float* __restrict__ sp, const float* __restrict__ tm,
    unsigned short* __restrict__ wsh, unsigned short* __restrict__ wsl) {
  const int tid = blockIdx.x * 256 + threadIdx.x;
  const int flat = tid * 8;
  const int b = flat / (MM * DD);
  const int rem = flat - b * (MM * DD);
  const int m = rem / DD;
  const int d = rem - m * DD;
  const float* src = (m < NSP)
      ? sp + ((size_t)b * NSP + m) * DD + d
      : tm + ((size_t)b * NTM + (m - NSP)) * DD + d;
  const float4* s4 = reinterpret_cast<const float4*>(src);
  float f[8];
  {
    float4 v0 = s4[0], v1 = s4[1];
    f[0]=v0.x; f[1]=v0.y; f[2]=v0.z; f[3]=v0.w;
    f[4]=v1.x; f[5]=v1.y; f[6]=v1.z; f[7]=v1.w;
  }
  ushort8 H, L;
  #pragma unroll
  for (int i = 0; i < 8; ++i) {
    const unsigned short hi = bf16_rn(f[i]);
    H[i] = hi;
    L[i] = bf16_rn(f[i] - bf16_f32(hi));
  }
  *reinterpret_cast<ushort8*>(wsh + flat) = H;
  *reinterpret_cast<ushort8*>(wsl + flat) = L;
}

// ---- main: persistent band-sweep, dbuf col panel ----
__global__ __launch_bounds__(256, 2) void stg_adj_kernel(
    const unsigned short* __restrict__ wsh,
    const unsigned short* __restrict__ wsl,
    float* __restrict__ out) {
  __shared__ unsigned char lds[2][32768];   // per buf: 16KB hi + 16KB lo

  // XCD pinning: x = wid%8 -> XCD; batch b owns residues {2b,2b+1}.
  const int wid = blockIdx.x;
  const int x = wid & 7;
  const int b = x >> 1;
  const int k = ((wid >> 3) << 1) + (x & 1);   // 0..127 within batch
  int tt0, len;
  if (k < 64) { tt0 = k * 13; len = 13; }
  else        { tt0 = 832 + (k - 64) * 12; len = 12; }

  const int tid = threadIdx.x;
  const int lane = tid & 63;
  const int wave = tid >> 6;
  const int wr = (wave >> 1) << 6;
  const int wc = (wave & 1) << 6;
  const int lr = lane & 15;
  const int lg = lane >> 4;

  const size_t pb = (size_t)b * MM * DD;
  const unsigned short* Xh = wsh + pb;
  const unsigned short* Xl = wsl + pb;
  const size_t cbase = (size_t)b * MM * MM;

  // staging geometry for this thread: 4 granules per component
  int srow[4], sg[4];
  #pragma unroll
  for (int kk = 0; kk < 4; ++kk) {
    const int G = tid + kk * 256;   // 0..1023
    srow[kk] = G >> 3;              // 0..127
    sg[kk]  = G & 7;                // 16B granule in row
  }

  // ---- prologue: stage tile tt0's col panel into buf 0 ----
  {
    const int bj = tt0 - (tt0 / NTILE) * NTILE;
    #pragma unroll
    for (int kk = 0; kk < 4; ++kk) {
      int grow = bj * BT + srow[kk]; grow = grow < MM ? grow : MM - 1;
      const ushort8 vh = *reinterpret_cast<const ushort8*>(Xh + (size_t)grow * DD + sg[kk] * 8);
      const ushort8 vl = *reinterpret_cast<const ushort8*>(Xl + (size_t)grow * DD + sg[kk] * 8);
      const unsigned db = (unsigned)srow[kk] * 128u + ((unsigned)(sg[kk] ^ (srow[kk] & 7)) << 4);
      *reinterpret_cast<ushort8*>(lds[0] + db) = vh;
      *reinterpret_cast<ushort8*>(lds[0] + 16384 + db) = vl;
    }
  }
  __syncthreads();

  int cur = 0;
  int cur_bi = -1;
  short8 ah[4][2], al[4][2];

  for (int i = 0; i < len; ++i) {
    const int tt = tt0 + i;
    const int bi = tt / NTILE;
    const int bj = tt - bi * NTILE;

    // reload A-frags (registers) on band change — rare (<= 2x per block)
    if (bi != cur_bi) {
      cur_bi = bi;
      #pragma unroll
      for (int m = 0; m < 4; ++m) {
        int ra = bi * BT + wr + m * 16 + lr; ra = ra < MM ? ra : MM - 1;
        const unsigned short* ph = Xh + (size_t)ra * DD;
        const unsigned short* pl = Xl + (size_t)ra * DD;
        #pragma unroll
        for (int ks = 0; ks < 2; ++ks) {
          ah[m][ks] = *reinterpret_cast<const short8*>(ph + (lg + ks * 4) * 8);
          al[m][ks] = *reinterpret_cast<const short8*>(pl + (lg + ks * 4) * 8);
        }
      }
    }

    // issue next tile's panel loads EARLY (latency hides under MFMA)
    ushort8 nreg[8];
    const bool have_next = (i + 1 < len);
    if (have_next) {
      const int tn = tt + 1;
      const int bjn = tn - (tn / NTILE) * NTILE;
      #pragma unroll
      for (int kk = 0; kk < 4; ++kk) {
        int grow = bjn * BT + srow[kk]; grow = grow < MM ? grow : MM - 1;
        nreg[kk]     = *reinterpret_cast<const ushort8*>(Xh + (size_t)grow * DD + sg[kk] * 8);
        nreg[kk + 4] = *reinterpret_cast<const ushort8*>(Xl + (size_t)grow * DD + sg[kk] * 8);
      }
    }

    // ---- compute from lds[cur] ----
    f32x4 acc[4][4];
    #pragma unroll
    for (int m = 0; m < 4; ++m)
      #pragma unroll
      for (int n = 0; n < 4; ++n)
        acc[m][n] = (f32x4){0.f, 0.f, 0.f, 0.f};

    #pragma unroll
    for (int ks = 0; ks < 2; ++ks) {
      short8 ch[4], cl[4];
      #pragma unroll
      for (int n = 0; n < 4; ++n) {
        const int rc = wc + n * 16 + lr;
        const unsigned gcb = (unsigned)rc * 128u + ((unsigned)((lg + ks * 4) ^ (rc & 7)) << 4);
        ch[n] = *reinterpret_cast<short8*>(lds[cur] + gcb);
        cl[n] = *reinterpret_cast<short8*>(lds[cur] + 16384 + gcb);
      }
      #pragma unroll
      for (int m = 0; m < 4; ++m) {
        #pragma unroll
        for (int n = 0; n < 4; ++n) {
          acc[m][n] = __builtin_amdgcn_mfma_f32_16x16x32_bf16(ch[n], ah[m][ks], acc[m][n], 0, 0, 0);
          acc[m][n] = __builtin_amdgcn_mfma_f32_16x16x32_bf16(ch[n], al[m][ks], acc[m][n], 0, 0, 0);
          acc[m][n] = __builtin_amdgcn_mfma_f32_16x16x32_bf16(cl[n], ah[m][ks], acc[m][n], 0, 0, 0);
        }
      }
    }

    // ---- epilogue: tanh(relu(x)+eye), float4 burst stores ----
    const int gr0 = bi * BT + wr;
    const int gc0 = bj * BT + wc;
    #pragma unroll
    for (int m = 0; m < 4; ++m) {
      const int gr = gr0 + m * 16 + lr;
      if (gr < MM) {
        float* rowp = out + cbase + (size_t)gr * MM;
        #pragma unroll
        for (int n = 0; n < 4; ++n) {
          const int gc = gc0 + n * 16 + lg * 4;
          if (gc < MM) {
            f32x4 v;
            #pragma unroll
            for (int q = 0; q < 4; ++q) {
              float xv = fmaxf(acc[m][n][q], 0.f);
              xv += (gr == gc + q) ? 1.f : 0.f;
              const float e = __builtin_amdgcn_exp2f(xv * 2.8853900817779268f);
              v[q] = 1.f - 2.f * __builtin_amdgcn_rcpf(e + 1.f);
            }
            *reinterpret_cast<f32x4*>(rowp + gc) = v;
          }
        }
      }
    }

    // ---- write staged regs to the other buffer, then sync ----
    if (have_next) {
      unsigned char* dstb = lds[cur ^ 1];
      #pragma unroll
      for (int kk = 0; kk < 4; ++kk) {
        const unsigned db = (unsigned)srow[kk] * 128u + ((unsigned)(sg[kk] ^ (srow[kk] & 7)) << 4);
        *reinterpret_cast<ushort8*>(dstb + db) = nreg[kk];
        *reinterpret_cast<ushort8*>(dstb + 16384 + db) = nreg[kk + 4];
      }
    }
    __syncthreads();
    cur ^= 1;
  }
}

extern "C" void kernel_launch(void* const* d_in, const int* in_sizes, int n_in,
                              void* d_out, int out_size, void* d_ws, size_t ws_size,
                              hipStream_t stream) {
  const float* sp = (const float*)d_in[0];
  const float* tm = (const float*)d_in[1];
  float* out = (float*)d_out;
  const int B = in_sizes[0] / (NSP * DD);   // = 4
  unsigned short* wsh = (unsigned short*)d_ws;
  unsigned short* wsl = wsh + (size_t)B * MM * DD;

  const int prep_threads = B * MM * DD / 8;
  stg_prep_kernel<<<dim3(prep_threads / 256), dim3(256), 0, stream>>>(sp, tm, wsh, wsl);

  stg_adj_kernel<<<dim3(512), dim3(256), 0, stream>>>(wsh, wsl, out);
}

// Round 10
// 137.533 us; speedup vs baseline: 1.0756x; 1.0756x over previous
//
#include <hip/hip_runtime.h>

// STGraphConstructor: adj[b] = tanh(relu(A_b A_b^T) + I), A_b = [5096 x 64] fp32.
// R10: R8 structure + higher store-phase coverage.
//  - R9 lesson: never barrier after stores (vmcnt(0) drains them serially).
//    Page continuation across tiles is physically meaningless (pages close in ns);
//    only within-burst contiguity + concurrent-phase coverage matter.
//  - R8 duty-cycle: store drain ~50% of block lifetime x 2 blocks/CU = 1.0
//    coverage (marginal). This round: drop row-panel LDS (A-frags direct from
//    L2 per ks, as validated in R9), LDS 64->32KB, __launch_bounds__(256,3)
//    => 3 blocks/CU, 1.5x store coverage, halved staging + faster cold start.
//  - Everything proven kept: prep kernel, hi/lo x3 MFMA, swapped operands,
//    XOR-swizzled col panel, exp2-tanh, float4 burst stores, grid(40,40,4).

#define NSP 5000
#define NTM 96
#define MM  5096
#define DD  64
#define BT  128
#define NTILE 40   // ceil(5096/128)

typedef __attribute__((ext_vector_type(8))) short short8;
typedef __attribute__((ext_vector_type(8))) unsigned short ushort8;
typedef __attribute__((ext_vector_type(4))) float f32x4;

__device__ __forceinline__ unsigned short bf16_rn(float x) {
  unsigned u = __float_as_uint(x);
  u += 0x7FFFu + ((u >> 16) & 1u);
  return (unsigned short)(u >> 16);
}
__device__ __forceinline__ float bf16_f32(unsigned short s) {
  return __uint_as_float(((unsigned)s) << 16);
}

// ---- prep: convert concat(sp,tm) [B][MM][DD] fp32 -> hi/lo bf16 panels ----
__global__ __launch_bounds__(256) void stg_prep_kernel(
    const float* __restrict__ sp, const float* __restrict__ tm,
    unsigned short* __restrict__ wsh, unsigned short* __restrict__ wsl) {
  const int tid = blockIdx.x * 256 + threadIdx.x;
  const int flat = tid * 8;
  const int b = flat / (MM * DD);
  const int rem = flat - b * (MM * DD);
  const int m = rem / DD;
  const int d = rem - m * DD;
  const float* src = (m < NSP)
      ? sp + ((size_t)b * NSP + m) * DD + d
      : tm + ((size_t)b * NTM + (m - NSP)) * DD + d;
  const float4* s4 = reinterpret_cast<const float4*>(src);
  float f[8];
  {
    float4 v0 = s4[0], v1 = s4[1];
    f[0]=v0.x; f[1]=v0.y; f[2]=v0.z; f[3]=v0.w;
    f[4]=v1.x; f[5]=v1.y; f[6]=v1.z; f[7]=v1.w;
  }
  ushort8 H, L;
  #pragma unroll
  for (int i = 0; i < 8; ++i) {
    const unsigned short hi = bf16_rn(f[i]);
    H[i] = hi;
    L[i] = bf16_rn(f[i] - bf16_f32(hi));
  }
  *reinterpret_cast<ushort8*>(wsh + flat) = H;
  *reinterpret_cast<ushort8*>(wsl + flat) = L;
}

// ---- main: 128x128 tile, col panel in 32KB LDS, A-frags direct from L2 ----
__global__ __launch_bounds__(256, 3) void stg_adj_kernel(
    const unsigned short* __restrict__ wsh,
    const unsigned short* __restrict__ wsl,
    float* __restrict__ out) {
  __shared__ unsigned char lds[32768];   // col panel: 16KB hi + 16KB lo
  const int bi = blockIdx.x;
  const int bj = blockIdx.y;
  const int b  = blockIdx.z;
  const int t  = threadIdx.x;

  const size_t pb = (size_t)b * MM * DD;
  const unsigned short* Xh = wsh + pb;
  const unsigned short* Xl = wsl + pb;

  // ---- stage col panel (coalesced 16B loads, XOR-swizzled rows) ----
  #pragma unroll
  for (int kk = 0; kk < 4; ++kk) {
    const int G = t + kk * 256;          // granule 0..1023
    const int row = G >> 3;              // 0..127
    const int g = G & 7;                 // 16B granule within row
    int grow = bj * BT + row; grow = grow < MM ? grow : MM - 1;
    const ushort8 vh = *reinterpret_cast<const ushort8*>(Xh + (size_t)grow * DD + g * 8);
    const ushort8 vl = *reinterpret_cast<const ushort8*>(Xl + (size_t)grow * DD + g * 8);
    const unsigned db = (unsigned)row * 128u + ((unsigned)(g ^ (row & 7)) << 4);
    *reinterpret_cast<ushort8*>(lds + db) = vh;
    *reinterpret_cast<ushort8*>(lds + 16384 + db) = vl;
  }
  __syncthreads();

  // ---- compute: wave owns 64x64 quadrant ----
  const int lane = t & 63;
  const int wave = t >> 6;
  const int wr = (wave >> 1) << 6;
  const int wc = (wave & 1) << 6;
  const int lr = lane & 15;
  const int lg = lane >> 4;

  f32x4 acc[4][4];
  #pragma unroll
  for (int m = 0; m < 4; ++m)
    #pragma unroll
    for (int n = 0; n < 4; ++n)
      acc[m][n] = (f32x4){0.f, 0.f, 0.f, 0.f};

  #pragma unroll
  for (int ks = 0; ks < 2; ++ks) {
    // A-frags direct from global (L2-hit): 16 rows x contiguous 16B per lane
    short8 ah[4], al[4];
    #pragma unroll
    for (int m = 0; m < 4; ++m) {
      int ra = bi * BT + wr + m * 16 + lr; ra = ra < MM ? ra : MM - 1;
      const size_t o = (size_t)ra * DD + (lg + ks * 4) * 8;
      ah[m] = *reinterpret_cast<const short8*>(Xh + o);
      al[m] = *reinterpret_cast<const short8*>(Xl + o);
    }
    // col frags from swizzled LDS
    short8 ch[4], cl[4];
    #pragma unroll
    for (int n = 0; n < 4; ++n) {
      const int rc = wc + n * 16 + lr;
      const unsigned gcb = (unsigned)rc * 128u + ((unsigned)((lg + ks * 4) ^ (rc & 7)) << 4);
      ch[n] = *reinterpret_cast<short8*>(lds + gcb);
      cl[n] = *reinterpret_cast<short8*>(lds + 16384 + gcb);
    }
    // swapped operands: lane holds row gr0+m*16+lr, cols gc0+n*16+lg*4+q
    #pragma unroll
    for (int m = 0; m < 4; ++m) {
      #pragma unroll
      for (int n = 0; n < 4; ++n) {
        acc[m][n] = __builtin_amdgcn_mfma_f32_16x16x32_bf16(ch[n], ah[m], acc[m][n], 0, 0, 0);
        acc[m][n] = __builtin_amdgcn_mfma_f32_16x16x32_bf16(ch[n], al[m], acc[m][n], 0, 0, 0);
        acc[m][n] = __builtin_amdgcn_mfma_f32_16x16x32_bf16(cl[n], ah[m], acc[m][n], 0, 0, 0);
      }
    }
  }

  // ---- epilogue: tanh(relu(x)+eye), float4 burst stores, no trailing barrier ----
  const size_t cbase = (size_t)b * MM * MM;
  const int gr0 = bi * BT + wr;
  const int gc0 = bj * BT + wc;
  #pragma unroll
  for (int m = 0; m < 4; ++m) {
    const int gr = gr0 + m * 16 + lr;
    if (gr < MM) {
      float* rowp = out + cbase + (size_t)gr * MM;
      #pragma unroll
      for (int n = 0; n < 4; ++n) {
        const int gc = gc0 + n * 16 + lg * 4;
        if (gc < MM) {   // gc, MM multiples of 4 => whole float4 in bounds
          f32x4 v;
          #pragma unroll
          for (int q = 0; q < 4; ++q) {
            float xv = fmaxf(acc[m][n][q], 0.f);
            xv += (gr == gc + q) ? 1.f : 0.f;
            const float e = __builtin_amdgcn_exp2f(xv * 2.8853900817779268f);
            v[q] = 1.f - 2.f * __builtin_amdgcn_rcpf(e + 1.f);
          }
          *reinterpret_cast<f32x4*>(rowp + gc) = v;
        }
      }
    }
  }
}

extern "C" void kernel_launch(void* const* d_in, const int* in_sizes, int n_in,
                              void* d_out, int out_size, void* d_ws, size_t ws_size,
                              hipStream_t stream) {
  const float* sp = (const float*)d_in[0];
  const float* tm = (const float*)d_in[1];
  float* out = (float*)d_out;
  const int B = in_sizes[0] / (NSP * DD);   // = 4
  unsigned short* wsh = (unsigned short*)d_ws;
  unsigned short* wsl = wsh + (size_t)B * MM * DD;

  const int prep_threads = B * MM * DD / 8;
  stg_prep_kernel<<<dim3(prep_threads / 256), dim3(256), 0, stream>>>(sp, tm, wsh, wsl);

  dim3 grid(NTILE, NTILE, B);
  stg_adj_kernel<<<grid, dim3(256), 0, stream>>>(wsh, wsl, out);
}

// Round 11
// 132.846 us; speedup vs baseline: 1.1136x; 1.0353x over previous
//
#include <hip/hip_runtime.h>

// STGraphConstructor: adj[b] = tanh(relu(A_b A_b^T) + I), A_b = [5096 x 64] fp32.
// R11: symmetry — compute upper-triangle tiles once, store direct + mirrored.
//  - Law (R3/R4/R10): fragment-shaped loads must come from LDS; only coalesced
//    loads touch global. R8 (both panels LDS) = 109.2 us is the base.
//  - R8 store duty ~30% x 2 blk/CU => ~50% store-pipe coverage (~3.9 TB/s).
//    Halving MFMA+staging+VALU per stored byte (tile computed once, stored twice)
//    raises duty to ~0.46 => coverage ~0.71.
//  - Mirror store = scattered 4B (R1 proved L2 merges); direct = float4 bursts.
//    All stores at block end, NO barrier after stores (R9 lesson).
//  - Diagonal blocks: single panel staged, eye-add, no mirror.

#define NSP 5000
#define NTM 96
#define MM  5096
#define DD  64
#define BT  128
#define NTRI 820   // 40*41/2 upper-triangle tile pairs per batch

typedef __attribute__((ext_vector_type(8))) short short8;
typedef __attribute__((ext_vector_type(8))) unsigned short ushort8;
typedef __attribute__((ext_vector_type(4))) float f32x4;

__device__ __forceinline__ unsigned short bf16_rn(float x) {
  unsigned u = __float_as_uint(x);
  u += 0x7FFFu + ((u >> 16) & 1u);
  return (unsigned short)(u >> 16);
}
__device__ __forceinline__ float bf16_f32(unsigned short s) {
  return __uint_as_float(((unsigned)s) << 16);
}

// ---- prep: convert concat(sp,tm) [B][MM][DD] fp32 -> hi/lo bf16 panels ----
__global__ __launch_bounds__(256) void stg_prep_kernel(
    const float* __restrict__ sp, const float* __restrict__ tm,
    unsigned short* __restrict__ wsh, unsigned short* __restrict__ wsl) {
  const int tid = blockIdx.x * 256 + threadIdx.x;
  const int flat = tid * 8;
  const int b = flat / (MM * DD);
  const int rem = flat - b * (MM * DD);
  const int m = rem / DD;
  const int d = rem - m * DD;
  const float* src = (m < NSP)
      ? sp + ((size_t)b * NSP + m) * DD + d
      : tm + ((size_t)b * NTM + (m - NSP)) * DD + d;
  const float4* s4 = reinterpret_cast<const float4*>(src);
  float f[8];
  {
    float4 v0 = s4[0], v1 = s4[1];
    f[0]=v0.x; f[1]=v0.y; f[2]=v0.z; f[3]=v0.w;
    f[4]=v1.x; f[5]=v1.y; f[6]=v1.z; f[7]=v1.w;
  }
  ushort8 H, L;
  #pragma unroll
  for (int i = 0; i < 8; ++i) {
    const unsigned short hi = bf16_rn(f[i]);
    H[i] = hi;
    L[i] = bf16_rn(f[i] - bf16_f32(hi));
  }
  *reinterpret_cast<ushort8*>(wsh + flat) = H;
  *reinterpret_cast<ushort8*>(wsl + flat) = L;
}

// ---- main: upper-triangle 128x128 tile, stored direct + mirrored ----
__global__ __launch_bounds__(256, 2) void stg_adj_kernel(
    const unsigned short* __restrict__ wsh,
    const unsigned short* __restrict__ wsl,
    float* __restrict__ out) {
  __shared__ unsigned char lds[65536];   // RH, RL, CH, CL (16KB each)
  const int p = blockIdx.x;
  const int b = blockIdx.y;

  // decode triangular pair (bi <= bj): S(bi) = bi*(81-bi)/2
  int bi = (int)((81.0f - sqrtf(6561.0f - 8.0f * (float)p)) * 0.5f);
  bi = bi < 0 ? 0 : (bi > 39 ? 39 : bi);
  while (bi > 0 && bi * (81 - bi) / 2 > p) --bi;
  while ((bi + 1) * (81 - (bi + 1)) / 2 <= p) ++bi;
  const int bj = bi + (p - bi * (81 - bi) / 2);
  const bool diag = (bi == bj);

  const int t = threadIdx.x;
  const size_t pb = (size_t)b * MM * DD;
  const unsigned short* Xh = wsh + pb;
  const unsigned short* Xl = wsl + pb;

  // ---- stage panels (coalesced 16B loads, XOR-swizzled rows) ----
  const int npanel = diag ? 2 : 4;
  for (int comp = 0; comp < npanel; ++comp) {
    const int tbase = (comp < 2 ? bi : bj) * BT;
    const unsigned short* src = (comp & 1) ? Xl : Xh;
    unsigned char* dst = lds + comp * 16384;
    #pragma unroll
    for (int k = 0; k < 4; ++k) {
      const int G = t + k * 256;
      const int row = G >> 3;
      const int g = G & 7;
      int grow = tbase + row; grow = grow < MM ? grow : MM - 1;
      const ushort8 v = *reinterpret_cast<const ushort8*>(src + (size_t)grow * DD + g * 8);
      *reinterpret_cast<ushort8*>(dst + row * 128 + ((g ^ (row & 7)) << 4)) = v;
    }
  }
  __syncthreads();

  // ---- compute: wave owns 64x64 quadrant, hi/lo x3 MFMA ----
  const int lane = t & 63;
  const int wave = t >> 6;
  const int wr = (wave >> 1) << 6;
  const int wc = (wave & 1) << 6;
  const int lr = lane & 15;
  const int lg = lane >> 4;

  unsigned char* chb = diag ? lds : (lds + 32768);
  unsigned char* clb = chb + 16384;

  f32x4 acc[4][4];
  #pragma unroll
  for (int m = 0; m < 4; ++m)
    #pragma unroll
    for (int n = 0; n < 4; ++n)
      acc[m][n] = (f32x4){0.f, 0.f, 0.f, 0.f};

  #pragma unroll
  for (int ks = 0; ks < 2; ++ks) {
    short8 ah[4], al[4], ch[4], cl[4];
    #pragma unroll
    for (int m = 0; m < 4; ++m) {
      const int ra = wr + m * 16 + lr;
      const unsigned ga = (unsigned)((lg + ks * 4) ^ (ra & 7)) << 4;
      ah[m] = *reinterpret_cast<short8*>(lds +         ra * 128 + ga);
      al[m] = *reinterpret_cast<short8*>(lds + 16384 + ra * 128 + ga);
      const int rc = wc + m * 16 + lr;
      const unsigned gc_ = (unsigned)((lg + ks * 4) ^ (rc & 7)) << 4;
      ch[m] = *reinterpret_cast<short8*>(chb + rc * 128 + gc_);
      cl[m] = *reinterpret_cast<short8*>(clb + rc * 128 + gc_);
    }
    // swapped operands: lane holds row gr0+m*16+lr, cols gc0+n*16+lg*4+q
    #pragma unroll
    for (int m = 0; m < 4; ++m) {
      #pragma unroll
      for (int n = 0; n < 4; ++n) {
        acc[m][n] = __builtin_amdgcn_mfma_f32_16x16x32_bf16(ch[n], ah[m], acc[m][n], 0, 0, 0);
        acc[m][n] = __builtin_amdgcn_mfma_f32_16x16x32_bf16(ch[n], al[m], acc[m][n], 0, 0, 0);
        acc[m][n] = __builtin_amdgcn_mfma_f32_16x16x32_bf16(cl[n], ah[m], acc[m][n], 0, 0, 0);
      }
    }
  }

  // ---- epilogue: relu, (diag) eye, tanh — transform acc in place ----
  const int gr0 = bi * BT + wr;
  const int gc0 = bj * BT + wc;
  #pragma unroll
  for (int m = 0; m < 4; ++m)
    #pragma unroll
    for (int n = 0; n < 4; ++n)
      #pragma unroll
      for (int q = 0; q < 4; ++q)
        acc[m][n][q] = fmaxf(acc[m][n][q], 0.f);
  if (diag) {
    #pragma unroll
    for (int m = 0; m < 4; ++m)
      #pragma unroll
      for (int n = 0; n < 4; ++n)
        #pragma unroll
        for (int q = 0; q < 4; ++q)
          if ((gr0 + m * 16 + lr) == (gc0 + n * 16 + lg * 4 + q)) acc[m][n][q] += 1.f;
  }
  #pragma unroll
  for (int m = 0; m < 4; ++m)
    #pragma unroll
    for (int n = 0; n < 4; ++n)
      #pragma unroll
      for (int q = 0; q < 4; ++q) {
        const float e = __builtin_amdgcn_exp2f(acc[m][n][q] * 2.8853900817779268f);
        acc[m][n][q] = 1.f - 2.f * __builtin_amdgcn_rcpf(e + 1.f);
      }

  // ---- direct stores: float4 bursts ----
  const size_t cbase = (size_t)b * MM * MM;
  #pragma unroll
  for (int m = 0; m < 4; ++m) {
    const int gr = gr0 + m * 16 + lr;
    if (gr < MM) {
      float* rowp = out + cbase + (size_t)gr * MM;
      #pragma unroll
      for (int n = 0; n < 4; ++n) {
        const int gc = gc0 + n * 16 + lg * 4;
        if (gc < MM)
          *reinterpret_cast<f32x4*>(rowp + gc) = acc[m][n];
      }
    }
  }

  // ---- mirror stores (bj,bi): scattered 4B, L2 merges (R1 evidence) ----
  if (!diag) {
    #pragma unroll
    for (int n = 0; n < 4; ++n) {
      #pragma unroll
      for (int q = 0; q < 4; ++q) {
        const int rowg = gc0 + n * 16 + lg * 4 + q;
        if (rowg < MM) {
          float* rowp = out + cbase + (size_t)rowg * MM;
          #pragma unroll
          for (int m = 0; m < 4; ++m) {
            const int colg = gr0 + m * 16 + lr;
            if (colg < MM) rowp[colg] = acc[m][n][q];
          }
        }
      }
    }
  }
}

extern "C" void kernel_launch(void* const* d_in, const int* in_sizes, int n_in,
                              void* d_out, int out_size, void* d_ws, size_t ws_size,
                              hipStream_t stream) {
  const float* sp = (const float*)d_in[0];
  const float* tm = (const float*)d_in[1];
  float* out = (float*)d_out;
  const int B = in_sizes[0] / (NSP * DD);   // = 4
  unsigned short* wsh = (unsigned short*)d_ws;
  unsigned short* wsl = wsh + (size_t)B * MM * DD;

  const int prep_threads = B * MM * DD / 8;
  stg_prep_kernel<<<dim3(prep_threads / 256), dim3(256), 0, stream>>>(sp, tm, wsh, wsl);

  stg_adj_kernel<<<dim3(NTRI, B), dim3(256), 0, stream>>>(wsh, wsl, out);
}